// Round 13
// baseline (119.713 us; speedup 1.0000x reference)
//
#include <hip/hip_runtime.h>
#include <hip/hip_bf16.h>
#include <math.h>

#define NH 4
#define DK 32
#define CC 128
#define HW 56
#define SHIFT 3
#define NTOK 12544   // 4*56*56 == 256*49
#define S_GLB 3136
#define VTW_STRIDE 12608
#define SCALE_L2E 0.25503488f  // log2(e)/sqrt(32): exp2-domain softmax scale

typedef unsigned short u16;
typedef short bf16x8 __attribute__((ext_vector_type(8)));
typedef unsigned short u16x8 __attribute__((ext_vector_type(8)));
typedef float f32x4 __attribute__((ext_vector_type(4)));

static __device__ __forceinline__ u16 f2bf(float f) {
  unsigned int b = __builtin_bit_cast(unsigned int, f);
  return (u16)((b + 0x7FFFu + ((b >> 16) & 1u)) >> 16);
}
static __device__ __forceinline__ unsigned pk2bf(float a, float b) {
  unsigned r;
  asm("v_cvt_pk_bf16_f32 %0, %1, %2" : "=v"(r) : "v"(a), "v"(b));
  return r;
}
static __device__ __forceinline__ float fexp2(float x) {
  float r;
  asm("v_exp_f32 %0, %1" : "=v"(r) : "v"(x));
  return r;
}
static __device__ __forceinline__ void gload16(const void* g, void* l) {
  __builtin_amdgcn_global_load_lds(
      (const __attribute__((address_space(1))) unsigned int*)g,
      (__attribute__((address_space(3))) unsigned int*)l, 16, 0, 0);
}

// ---------------- prep: weight converts (blocks 0..767) + shift-gather (rest)
__global__ __launch_bounds__(256) void prep_k(
    const float* __restrict__ w1, const float* __restrict__ w2,
    const float* __restrict__ wq, const float* __restrict__ wk,
    const float* __restrict__ wv, const float* __restrict__ wo,
    const float* __restrict__ x,
    u16* __restrict__ w1t, u16* __restrict__ w2t,
    u16* __restrict__ wqkvt, u16* __restrict__ wot, u16* __restrict__ xg) {
  if (blockIdx.x < 768) {
    const int idx = blockIdx.x * 256 + threadIdx.x;
    if (idx < 65536) {            // w1 [128][512] -> w1t [512][128]
      const int c = idx >> 7, r = idx & 127;
      w1t[idx] = f2bf(w1[r * 512 + c]);
    } else if (idx < 131072) {    // w2 [512][128] -> w2t [128][512]
      const int o = idx - 65536;
      const int c = o / 512, r = o - c * 512;
      w2t[o] = f2bf(w2[r * 128 + c]);
    } else {                      // four 128x128 -> transposed
      const int o = idx - 131072;
      const int which = o >> 14, oo = o & 16383;
      const int c = oo >> 7, r = oo & 127;
      const float* src = (which == 0) ? wq : (which == 1) ? wk : (which == 2) ? wv : wo;
      u16* dst = (which < 3) ? (wqkvt + which * 16384) : wot;
      dst[oo] = f2bf(src[r * 128 + c]);
    }
  } else {
    const int bid = blockIdx.x - 768;
    const int t = bid * 2 + (threadIdx.x >> 7);
    const int c = threadIdx.x & 127;
    const int win = t / 49, tok = t % 49;
    const int b = win >> 6, wrem = win & 63;
    const int wi = wrem >> 3, wj = wrem & 7;
    const int i = tok / 7, j = tok % 7;
    int hh = wi * 7 + i + SHIFT; if (hh >= HW) hh -= HW;
    int ww = wj * 7 + j + SHIFT; if (ww >= HW) ww -= HW;
    xg[(size_t)t * CC + c] = f2bf(x[((size_t)(b * HW + hh) * HW + ww) * CC + c]);
  }
}

// ---------------- fused QKV GEMM. PATH 0: window layout, PATH 1: global layout.
template <int PATH>
__global__ __launch_bounds__(256) void qkv_gemm_k(
    const u16* __restrict__ xin, const u16* __restrict__ wqkvt,
    const float* __restrict__ bq, const float* __restrict__ bk,
    const float* __restrict__ bv,
    u16* __restrict__ qo, u16* __restrict__ ko, u16* __restrict__ vto) {
  __shared__ __align__(16) u16 xs[64][136];
  __shared__ __align__(16) u16 wt[64][136];
  const int tid = threadIdx.x;
  const int w = tid >> 6, lane = tid & 63;
  const int lo = lane & 15, hi = lane >> 4, hi4 = hi * 4;
  const int m0 = blockIdx.x * 64;
  const int widx = blockIdx.y >> 1;
  const int n0 = (blockIdx.y & 1) * 64;
  {
    const int r = tid >> 2, sg = tid & 3;
    const u16* sx = &xin[(size_t)(m0 + r) * CC + sg * 32];
    const u16* sw = &wqkvt[(size_t)widx * CC * CC + (size_t)(n0 + r) * CC + sg * 32];
#pragma unroll
    for (int j = 0; j < 4; ++j) {
      *reinterpret_cast<u16x8*>(&xs[r][sg * 32 + j * 8]) = *reinterpret_cast<const u16x8*>(&sx[j * 8]);
      *reinterpret_cast<u16x8*>(&wt[r][sg * 32 + j * 8]) = *reinterpret_cast<const u16x8*>(&sw[j * 8]);
    }
  }
  __syncthreads();
  if (widx < 2) {
    const float* bias = (widx == 0) ? bq : bk;
    u16* outp = (widx == 0) ? qo : ko;
    const float oscale = (widx == 0) ? SCALE_L2E : 1.0f;
    f32x4 acc[4];
#pragma unroll
    for (int st = 0; st < 4; ++st) {
      const float b_ = bias[n0 + st * 16 + lo];
      acc[st] = (f32x4){b_, b_, b_, b_};
    }
#pragma unroll
    for (int kk = 0; kk < 4; ++kk) {
      const bf16x8 af = *reinterpret_cast<const bf16x8*>(&xs[w * 16 + lo][kk * 32 + 8 * hi]);
#pragma unroll
      for (int st = 0; st < 4; ++st) {
        const bf16x8 bfr = *reinterpret_cast<const bf16x8*>(&wt[st * 16 + lo][kk * 32 + 8 * hi]);
        acc[st] = __builtin_amdgcn_mfma_f32_16x16x32_bf16(af, bfr, acc[st], 0, 0, 0);
      }
    }
#pragma unroll
    for (int r = 0; r < 4; ++r) {
      const int mm = m0 + w * 16 + hi4 + r;
      size_t rowbase, hstride;
      if (PATH == 0) {
        const int win = mm / 49, tok = mm - win * 49;
        rowbase = ((size_t)(win * 4) * 49 + tok) * DK;
        hstride = (size_t)49 * DK;
      } else {
        const int b = mm / S_GLB, s = mm - b * S_GLB;
        rowbase = ((size_t)(b * 4) * S_GLB + s) * DK;
        hstride = (size_t)S_GLB * DK;
      }
#pragma unroll
      for (int st = 0; st < 4; ++st) {
        const int c = n0 + st * 16 + lo, h = c >> 5, d = c & 31;
        outp[rowbase + (size_t)h * hstride + d] = f2bf(acc[st][r] * oscale);
      }
    }
  } else {
    f32x4 bias4;
#pragma unroll
    for (int r = 0; r < 4; ++r) bias4[r] = bv[n0 + w * 16 + hi4 + r];
    f32x4 acc[4];
#pragma unroll
    for (int st = 0; st < 4; ++st) acc[st] = bias4;
#pragma unroll
    for (int kk = 0; kk < 4; ++kk) {
      const bf16x8 af = *reinterpret_cast<const bf16x8*>(&wt[w * 16 + lo][kk * 32 + 8 * hi]);
#pragma unroll
      for (int st = 0; st < 4; ++st) {
        const bf16x8 bfr = *reinterpret_cast<const bf16x8*>(&xs[st * 16 + lo][kk * 32 + 8 * hi]);
        acc[st] = __builtin_amdgcn_mfma_f32_16x16x32_bf16(af, bfr, acc[st], 0, 0, 0);
      }
    }
#pragma unroll
    for (int st = 0; st < 4; ++st) {
      const int mm = m0 + st * 16 + lo;
#pragma unroll
      for (int r = 0; r < 4; ++r) {
        const int c = n0 + w * 16 + hi4 + r;
        if (PATH == 0) {
          vto[(size_t)c * VTW_STRIDE + mm] = f2bf(acc[st][r]);
        } else {
          const int b = mm / S_GLB, s = mm - b * S_GLB;
          vto[((size_t)b * CC + c) * S_GLB + s] = f2bf(acc[st][r]);
        }
      }
    }
  }
}

// ---------------- window attention: no-max exp2 softmax, l via ones-MFMA
__global__ __launch_bounds__(256) void win_attn_k(
    const u16* __restrict__ qw, const u16* __restrict__ kw,
    const u16* __restrict__ vtw, u16* __restrict__ aow) {
  __shared__ __align__(16) u16 psh[4][16][72];
  const int tid = threadIdx.x;
  const int wvi = tid >> 6, lane = tid & 63;
  const int lo = lane & 15, hi = lane >> 4, hi4 = hi * 4;
  const int wh = blockIdx.x * 4 + wvi;
  const int win = wh >> 2, hd = wh & 3;
  const f32x4 zero4 = {0.f, 0.f, 0.f, 0.f};
  bf16x8 ones;
#pragma unroll
  for (int j = 0; j < 8; ++j) ones[j] = (short)0x3F80;

  bf16x8 kf[4], vf[2][2];
#pragma unroll
  for (int st = 0; st < 4; ++st)
    kf[st] = *reinterpret_cast<const bf16x8*>(&kw[((size_t)wh * 49 + st * 16 + lo) * DK + 8 * hi]);
#pragma unroll
  for (int dst = 0; dst < 2; ++dst)
#pragma unroll
    for (int kch = 0; kch < 2; ++kch)
      vf[dst][kch] = *reinterpret_cast<const bf16x8*>(
          &vtw[(size_t)(hd * DK + dst * 16 + lo) * VTW_STRIDE + win * 49 + kch * 32 + 8 * hi]);

#pragma unroll
  for (int g = 0; g < 4; ++g) {
    const bf16x8 qf = *reinterpret_cast<const bf16x8*>(
        &qw[((size_t)wh * 49 + g * 16 + lo) * DK + 8 * hi]);
    f32x4 s4[4];
#pragma unroll
    for (int st = 0; st < 4; ++st) {
      s4[st] = __builtin_amdgcn_mfma_f32_16x16x32_bf16(kf[st], qf, zero4, 0, 0, 0);
#pragma unroll
      for (int r = 0; r < 4; ++r)
        if (st * 16 + hi4 + r >= 49) s4[st][r] = -1e30f;  // mask pad keys -> p=0
    }
#pragma unroll
    for (int st = 0; st < 4; ++st) {
      uint2 pk;
      pk.x = pk2bf(fexp2(s4[st][0]), fexp2(s4[st][1]));
      pk.y = pk2bf(fexp2(s4[st][2]), fexp2(s4[st][3]));
      *reinterpret_cast<uint2*>(&psh[wvi][lo][st * 16 + hi4]) = pk;
    }
    asm volatile("" ::: "memory");
    f32x4 acc0 = zero4, acc1 = zero4, lacc = zero4;
#pragma unroll
    for (int kch = 0; kch < 2; ++kch) {
      const bf16x8 pa = *reinterpret_cast<const bf16x8*>(&psh[wvi][lo][kch * 32 + 8 * hi]);
      acc0 = __builtin_amdgcn_mfma_f32_16x16x32_bf16(pa, vf[0][kch], acc0, 0, 0, 0);
      acc1 = __builtin_amdgcn_mfma_f32_16x16x32_bf16(pa, vf[1][kch], acc1, 0, 0, 0);
      lacc = __builtin_amdgcn_mfma_f32_16x16x32_bf16(pa, ones, lacc, 0, 0, 0);
    }
#pragma unroll
    for (int r = 0; r < 4; ++r) {
      const int qrow = g * 16 + hi4 + r;
      if (qrow < 49) {
        const float rl = 1.0f / lacc[r];
        const size_t tw = (size_t)win * 49 + qrow;
        aow[tw * CC + hd * DK + lo] = f2bf(acc0[r] * rl);
        aow[tw * CC + hd * DK + 16 + lo] = f2bf(acc1[r] * rl);
      }
    }
  }
}

// ---------------- global attention v7: 2 waves x 32q (K/V frag reuse across
// 2 q-groups halves K/V LDS reads per q). Split-K z=2, XCD-bijective swizzle.
__global__ __launch_bounds__(128) void glb_attn_k(
    const u16* __restrict__ qg, const u16* __restrict__ kg,
    const u16* __restrict__ vtg, float* __restrict__ po, float* __restrict__ pl) {
  __shared__ __align__(16) u16 ksh[2][64][32];      // linear, conflict-free reads
  __shared__ __align__(16) u16 vtsh[2][32][64];     // content XOR-swizzled via source
  __shared__ __align__(16) u16 psh[2][2][16][64];   // [wave][qgroup], swizzled
  const int tid = threadIdx.x;
  const int w = tid >> 6, lane = tid & 63;
  const int lo = lane & 15, hi = lane >> 4, hi4 = hi * 4;
  // XCD-bijective swizzle: 1568 blocks = 8 XCDs x 196.
  const int wg = blockIdx.x;
  const int sid = (wg & 7) * 196 + (wg >> 3);
  const int sp = sid / 784;
  const int rem = sid - sp * 784;
  const int bh = rem / 49;
  const int q0 = (rem - bh * 49) * 64;
  const int kt_beg = sp * 25;
  const int kt_end = sp ? 49 : 25;
  const f32x4 zero4 = {0.f, 0.f, 0.f, 0.f};
  bf16x8 ones;
#pragma unroll
  for (int j = 0; j < 8; ++j) ones[j] = (short)0x3F80;

  // wave w owns q-rows [q0 + w*32, q0 + w*32 + 32) as 2 q-groups of 16
  const bf16x8 qf0 = *reinterpret_cast<const bf16x8*>(
      &qg[((size_t)bh * S_GLB + q0 + w * 32 + lo) * DK + 8 * hi]);
  const bf16x8 qf1 = *reinterpret_cast<const bf16x8*>(
      &qg[((size_t)bh * S_GLB + q0 + w * 32 + 16 + lo) * DK + 8 * hi]);
  const u16* kg0 = kg + (size_t)bh * S_GLB * DK;
  const u16* vg0 = vtg + (size_t)bh * DK * S_GLB;

  // staging: wave w stages K rows [w*32, w*32+32) (2 calls) and V^T rows
  // [w*16, w*16+16) (2 calls). V source pre-swizzled (row&7 == lane>>3).
  const u16* ksrc = kg0 + (size_t)(w * 32 + (lane >> 2)) * DK + (lane & 3) * 8;
  const u16* vsrc = vg0 + (size_t)(w * 16 + (lane >> 3)) * S_GLB + ((lane & 7) ^ (lane >> 3)) * 8;
  u16* const kdst[2] = {&ksh[0][w * 32][0], &ksh[1][w * 32][0]};
  u16* const vdst[2] = {&vtsh[0][w * 16][0], &vtsh[1][w * 16][0]};

  f32x4 oacc00 = zero4, oacc01 = zero4, lacc0 = zero4;
  f32x4 oacc10 = zero4, oacc11 = zero4, lacc1 = zero4;

  {
    const size_t ko = (size_t)kt_beg * 64 * DK, vo = (size_t)kt_beg * 64;
    gload16(ksrc + ko, kdst[0]);
    gload16(ksrc + ko + 16 * DK, kdst[0] + 16 * 32);
    gload16(vsrc + vo, vdst[0]);
    gload16(vsrc + vo + 8 * S_GLB, vdst[0] + 8 * 64);
  }
  __syncthreads();

  char* const pbase0 = (char*)&psh[w][0][lo][0];
  char* const pbase1 = (char*)&psh[w][1][lo][0];
  char* const vbase0 = (char*)&vtsh[0][0][0];
  const unsigned swz = (unsigned)(lo & 7) << 4;

  for (int kt = kt_beg; kt < kt_end; ++kt) {
    const int cur = (kt - kt_beg) & 1;
    if (kt + 1 < kt_end) {  // issue next-tile DMA before compute (2-phase)
      const size_t ko = (size_t)(kt + 1) * 64 * DK, vo = (size_t)(kt + 1) * 64;
      gload16(ksrc + ko, kdst[cur ^ 1]);
      gload16(ksrc + ko + 16 * DK, kdst[cur ^ 1] + 16 * 32);
      gload16(vsrc + vo, vdst[cur ^ 1]);
      gload16(vsrc + vo + 8 * S_GLB, vdst[cur ^ 1] + 8 * 64);
    }
    // S^T = K * Q^T for both q-groups; K frags loaded once, used twice
    bf16x8 kf[4];
#pragma unroll
    for (int st = 0; st < 4; ++st)
      kf[st] = *reinterpret_cast<const bf16x8*>(&ksh[cur][st * 16 + lo][8 * hi]);
    f32x4 s40[4], s41[4];
#pragma unroll
    for (int st = 0; st < 4; ++st) {
      s40[st] = __builtin_amdgcn_mfma_f32_16x16x32_bf16(kf[st], qf0, zero4, 0, 0, 0);
      s41[st] = __builtin_amdgcn_mfma_f32_16x16x32_bf16(kf[st], qf1, zero4, 0, 0, 0);
    }
    // p = exp2(s), pack to bf16, swizzled P stores
#pragma unroll
    for (int st = 0; st < 4; ++st) {
      uint2 pk0, pk1;
      pk0.x = pk2bf(fexp2(s40[st][0]), fexp2(s40[st][1]));
      pk0.y = pk2bf(fexp2(s40[st][2]), fexp2(s40[st][3]));
      pk1.x = pk2bf(fexp2(s41[st][0]), fexp2(s41[st][1]));
      pk1.y = pk2bf(fexp2(s41[st][2]), fexp2(s41[st][3]));
      const unsigned off = ((unsigned)(st * 32 + hi * 8)) ^ swz;
      *reinterpret_cast<uint2*>(pbase0 + off) = pk0;
      *reinterpret_cast<uint2*>(pbase1 + off) = pk1;
    }
    asm volatile("" ::: "memory");
    // PV + l via ones-MFMA; V frags loaded once, used by both q-groups
    char* const vrow0 = vbase0 + (size_t)cur * (32 * 64 * 2) + lo * 128;
#pragma unroll
    for (int kch = 0; kch < 2; ++kch) {
      const unsigned off = ((unsigned)(kch * 64 + hi * 16)) ^ swz;
      const bf16x8 v0 = *reinterpret_cast<const bf16x8*>(vrow0 + off);
      const bf16x8 v1 = *reinterpret_cast<const bf16x8*>(vrow0 + 16 * 128 + off);
      const bf16x8 pa0 = *reinterpret_cast<const bf16x8*>(pbase0 + off);
      const bf16x8 pa1 = *reinterpret_cast<const bf16x8*>(pbase1 + off);
      oacc00 = __builtin_amdgcn_mfma_f32_16x16x32_bf16(pa0, v0, oacc00, 0, 0, 0);
      oacc01 = __builtin_amdgcn_mfma_f32_16x16x32_bf16(pa0, v1, oacc01, 0, 0, 0);
      lacc0 = __builtin_amdgcn_mfma_f32_16x16x32_bf16(pa0, ones, lacc0, 0, 0, 0);
      oacc10 = __builtin_amdgcn_mfma_f32_16x16x32_bf16(pa1, v0, oacc10, 0, 0, 0);
      oacc11 = __builtin_amdgcn_mfma_f32_16x16x32_bf16(pa1, v1, oacc11, 0, 0, 0);
      lacc1 = __builtin_amdgcn_mfma_f32_16x16x32_bf16(pa1, ones, lacc1, 0, 0, 0);
    }
    __syncthreads();  // drains vmcnt: next tile landed; cur free to overwrite
  }

  const int b = bh >> 2, hd = bh & 3;
  float* pob = po + (size_t)sp * NTOK * CC;
#pragma unroll
  for (int r = 0; r < 4; ++r) {
    const size_t t0 = (size_t)b * S_GLB + q0 + w * 32 + hi4 + r;
    pob[t0 * CC + hd * DK + lo] = oacc00[r];
    pob[t0 * CC + hd * DK + 16 + lo] = oacc01[r];
    const size_t t1 = t0 + 16;
    pob[t1 * CC + hd * DK + lo] = oacc10[r];
    pob[t1 * CC + hd * DK + 16 + lo] = oacc11[r];
    if (lo == 0) {
      pl[((size_t)sp * 16 + bh) * S_GLB + q0 + w * 32 + hi4 + r] = lacc0[r];
      pl[((size_t)sp * 16 + bh) * S_GLB + q0 + w * 32 + 16 + hi4 + r] = lacc1[r];
    }
  }
}

// ---------------- output projection GEMM with FUSED LayerNorm epilogue.
template <int MODE>
__global__ __launch_bounds__(256) void proj_ln_k(
    const u16* __restrict__ ain, const float* __restrict__ po,
    const float* __restrict__ pl, const u16* __restrict__ wot,
    const float* __restrict__ bo, const float* __restrict__ resid,
    const float* __restrict__ lng, const float* __restrict__ lnb,
    float* __restrict__ xfo, u16* __restrict__ ybf) {
  __shared__ __align__(16) u16 xs[64][136];
  __shared__ __align__(16) u16 wt[128][136];
  const int tid = threadIdx.x;
  const int w = tid >> 6, lane = tid & 63;
  const int lo = lane & 15, hi = lane >> 4, hi4 = hi * 4;
  const int m0 = blockIdx.x * 64;
  {
    const int r = tid >> 2, sg = tid & 3;
    if (MODE == 0) {
      const u16* sx = &ain[(size_t)(m0 + r) * CC + sg * 32];
#pragma unroll
      for (int j = 0; j < 4; ++j)
        *reinterpret_cast<u16x8*>(&xs[r][sg * 32 + j * 8]) = *reinterpret_cast<const u16x8*>(&sx[j * 8]);
    } else {
      // fused split-K combine: head == sg (32 channels/head)
      const int mm = m0 + r;
      const int b = mm / S_GLB, s_ = mm - b * S_GLB;
      const float l0 = pl[((size_t)(b * 4 + sg)) * S_GLB + s_];
      const float l1 = pl[((size_t)(16 + b * 4 + sg)) * S_GLB + s_];
      const float rl = 1.0f / (l0 + l1);
      const float* pa = &po[(size_t)mm * CC + sg * 32];
      const float* pb = pa + (size_t)NTOK * CC;
#pragma unroll
      for (int j = 0; j < 32; j += 4) {
        const float4 a4 = *reinterpret_cast<const float4*>(&pa[j]);
        const float4 b4 = *reinterpret_cast<const float4*>(&pb[j]);
        uint2 pk;
        pk.x = pk2bf((a4.x + b4.x) * rl, (a4.y + b4.y) * rl);
        pk.y = pk2bf((a4.z + b4.z) * rl, (a4.w + b4.w) * rl);
        *reinterpret_cast<uint2*>(&xs[r][sg * 32 + j]) = pk;
      }
    }
    // weights: 128 rows x 128 cols
    const int r2 = tid >> 1, sg2 = tid & 1;
    const u16* sw = &wot[(size_t)r2 * CC + sg2 * 64];
#pragma unroll
    for (int j = 0; j < 8; ++j)
      *reinterpret_cast<u16x8*>(&wt[r2][sg2 * 64 + j * 8]) = *reinterpret_cast<const u16x8*>(&sw[j * 8]);
  }
  __syncthreads();
  f32x4 acc[8];
#pragma unroll
  for (int st = 0; st < 8; ++st) {
    const float b_ = bo[st * 16 + lo];
    acc[st] = (f32x4){b_, b_, b_, b_};
  }
#pragma unroll
  for (int kk = 0; kk < 4; ++kk) {
    const bf16x8 af = *reinterpret_cast<const bf16x8*>(&xs[w * 16 + lo][kk * 32 + 8 * hi]);
#pragma unroll
    for (int st = 0; st < 8; ++st) {
      const bf16x8 bfr = *reinterpret_cast<const bf16x8*>(&wt[st * 16 + lo][kk * 32 + 8 * hi]);
      acc[st] = __builtin_amdgcn_mfma_f32_16x16x32_bf16(af, bfr, acc[st], 0, 0, 0);
    }
  }
  float gv[8], bv2[8];
#pragma unroll
  for (int st = 0; st < 8; ++st) { gv[st] = lng[st * 16 + lo]; bv2[st] = lnb[st * 16 + lo]; }
#pragma unroll
  for (int r = 0; r < 4; ++r) {
    const int mm = m0 + w * 16 + hi4 + r;
    size_t trow;
    if (MODE == 0) {
      const int win = mm / 49, tok = mm - win * 49;
      const int b = win >> 6, wi = (win >> 3) & 7, wj = win & 7;
      const int ii = tok / 7, jj = tok - ii * 7;
      int hr = wi * 7 + ii + SHIFT; if (hr >= HW) hr -= HW;
      int wr = wj * 7 + jj + SHIFT; if (wr >= HW) wr -= HW;
      trow = (size_t)b * S_GLB + hr * HW + wr;
    } else {
      trow = (size_t)mm;
    }
    float v[8];
    float s = 0.f, sq = 0.f;
#pragma unroll
    for (int st = 0; st < 8; ++st) {
      float t_ = acc[st][r];
      if (MODE == 1) t_ += resid[trow * CC + st * 16 + lo];
      v[st] = t_;
      s += t_;
      sq += t_ * t_;
    }
    s += __shfl_xor(s, 1); s += __shfl_xor(s, 2); s += __shfl_xor(s, 4); s += __shfl_xor(s, 8);
    sq += __shfl_xor(sq, 1); sq += __shfl_xor(sq, 2); sq += __shfl_xor(sq, 4); sq += __shfl_xor(sq, 8);
    const float mu = s * 0.0078125f;
    const float rsig = rsqrtf(sq * 0.0078125f - mu * mu + 1e-5f);
#pragma unroll
    for (int st = 0; st < 8; ++st) {
      const size_t idx = trow * CC + st * 16 + lo;
      xfo[idx] = v[st];
      ybf[idx] = f2bf((v[st] - mu) * rsig * gv[st] + bv2[st]);
    }
  }
}

// ---------------- GEMM1 [NTOK,128]@[128,512] + gelu -> bf16
__global__ __launch_bounds__(256) void gemm1_k(
    const u16* __restrict__ ybf, const u16* __restrict__ w1t,
    const float* __restrict__ b1, u16* __restrict__ hb) {
  __shared__ __align__(16) u16 xs[64][136];
  __shared__ __align__(16) u16 wt[64][136];
  const int tid = threadIdx.x;
  const int w = tid >> 6, lane = tid & 63;
  const int lo = lane & 15, hi = lane >> 4;
  const int m0 = blockIdx.x * 64, n0 = blockIdx.y * 64;
  {
    const int r = tid >> 2, sg = tid & 3;
    const u16* src_x = &ybf[(size_t)(m0 + r) * CC + sg * 32];
    const u16* src_w = &w1t[(size_t)(n0 + r) * CC + sg * 32];
#pragma unroll
    for (int j = 0; j < 4; ++j) {
      *reinterpret_cast<u16x8*>(&xs[r][sg * 32 + j * 8]) = *reinterpret_cast<const u16x8*>(&src_x[j * 8]);
      *reinterpret_cast<u16x8*>(&wt[r][sg * 32 + j * 8]) = *reinterpret_cast<const u16x8*>(&src_w[j * 8]);
    }
  }
  __syncthreads();
  f32x4 acc[4];
#pragma unroll
  for (int st = 0; st < 4; ++st) {
    const float bv = b1[n0 + st * 16 + lo];
    acc[st] = (f32x4){bv, bv, bv, bv};
  }
#pragma unroll
  for (int kk = 0; kk < 4; ++kk) {
    const bf16x8 af = *reinterpret_cast<const bf16x8*>(&xs[w * 16 + lo][kk * 32 + 8 * hi]);
#pragma unroll
    for (int st = 0; st < 4; ++st) {
      const bf16x8 bfr = *reinterpret_cast<const bf16x8*>(&wt[st * 16 + lo][kk * 32 + 8 * hi]);
      acc[st] = __builtin_amdgcn_mfma_f32_16x16x32_bf16(af, bfr, acc[st], 0, 0, 0);
    }
  }
#pragma unroll
  for (int st = 0; st < 4; ++st) {
#pragma unroll
    for (int r = 0; r < 4; ++r) {
      const float val = acc[st][r];
      const float gel = 0.5f * val * (1.0f + erff(val * 0.70710678118f));
      hb[(size_t)(m0 + w * 16 + (hi << 2) + r) * 512 + n0 + st * 16 + lo] = f2bf(gel);
    }
  }
}

// ---------------- GEMM2 [NTOK,512]@[512,128] + residual -> out
__global__ __launch_bounds__(256) void gemm2_k(
    const u16* __restrict__ hb, const u16* __restrict__ w2t,
    const float* __restrict__ b2, const float* __restrict__ xf,
    float* __restrict__ out) {
  __shared__ __align__(16) u16 xs[64][136];
  __shared__ __align__(16) u16 wt[64][136];
  const int tid = threadIdx.x;
  const int w = tid >> 6, lane = tid & 63;
  const int lo = lane & 15, hi = lane >> 4;
  const int m0 = blockIdx.x * 64, n0 = blockIdx.y * 64;
  f32x4 acc[4];
#pragma unroll
  for (int st = 0; st < 4; ++st) {
    const float bv = b2[n0 + st * 16 + lo];
    acc[st] = (f32x4){bv, bv, bv, bv};
  }
  for (int kc = 0; kc < 4; ++kc) {
    if (kc) __syncthreads();
    {
      const int r = tid >> 2, sg = tid & 3;
      const u16* src_x = &hb[(size_t)(m0 + r) * 512 + kc * 128 + sg * 32];
      const u16* src_w = &w2t[(size_t)(n0 + r) * 512 + kc * 128 + sg * 32];
#pragma unroll
      for (int j = 0; j < 4; ++j) {
        *reinterpret_cast<u16x8*>(&xs[r][sg * 32 + j * 8]) = *reinterpret_cast<const u16x8*>(&src_x[j * 8]);
        *reinterpret_cast<u16x8*>(&wt[r][sg * 32 + j * 8]) = *reinterpret_cast<const u16x8*>(&src_w[j * 8]);
      }
    }
    __syncthreads();
#pragma unroll
    for (int kk = 0; kk < 4; ++kk) {
      const bf16x8 af = *reinterpret_cast<const bf16x8*>(&xs[w * 16 + lo][kk * 32 + 8 * hi]);
#pragma unroll
      for (int st = 0; st < 4; ++st) {
        const bf16x8 bfr = *reinterpret_cast<const bf16x8*>(&wt[st * 16 + lo][kk * 32 + 8 * hi]);
        acc[st] = __builtin_amdgcn_mfma_f32_16x16x32_bf16(af, bfr, acc[st], 0, 0, 0);
      }
    }
  }
#pragma unroll
  for (int st = 0; st < 4; ++st) {
#pragma unroll
    for (int r = 0; r < 4; ++r) {
      const size_t idx = (size_t)(m0 + w * 16 + (hi << 2) + r) * CC + n0 + st * 16 + lo;
      out[idx] = xf[idx] + acc[st][r];
    }
  }
}

extern "C" void kernel_launch(void* const* d_in, const int* in_sizes, int n_in,
                              void* d_out, int out_size, void* d_ws, size_t ws_size,
                              hipStream_t stream) {
  (void)in_sizes; (void)n_in; (void)out_size; (void)ws_size;
  const float* x   = (const float*)d_in[0];
  const float* wq  = (const float*)d_in[1];
  const float* bq  = (const float*)d_in[2];
  const float* wk  = (const float*)d_in[3];
  const float* bk  = (const float*)d_in[4];
  const float* wv  = (const float*)d_in[5];
  const float* bv  = (const float*)d_in[6];
  const float* wo  = (const float*)d_in[7];
  const float* bo  = (const float*)d_in[8];
  const float* w1  = (const float*)d_in[9];
  const float* b1  = (const float*)d_in[10];
  const float* w2  = (const float*)d_in[11];
  const float* b2  = (const float*)d_in[12];
  const float* g1  = (const float*)d_in[13];
  const float* be1 = (const float*)d_in[14];
  const float* g2  = (const float*)d_in[15];
  const float* be2 = (const float*)d_in[16];
  float* out = (float*)d_out;

  char* p = (char*)d_ws;
  auto alloc = [&](size_t bytes) { char* r = p; p += (bytes + 255) & ~(size_t)255; return r; };
  float* xf  = (float*)alloc((size_t)NTOK * CC * 4);
  u16* xg    = (u16*)alloc((size_t)NTOK * CC * 2);   // gather out / LN out (ybf)
  u16* qw    = (u16*)alloc((size_t)NTOK * CC * 2 + 4096);
  u16* kw    = (u16*)alloc((size_t)NTOK * CC * 2 + 4096);
  u16* vtw   = (u16*)alloc((size_t)CC * VTW_STRIDE * 2);
  u16* aow   = (u16*)alloc((size_t)NTOK * CC * 2);
  u16* hb    = (u16*)alloc((size_t)NTOK * 512 * 2);
  float* po  = (float*)alloc((size_t)2 * NTOK * CC * 4);
  float* pl  = (float*)alloc((size_t)2 * 16 * S_GLB * 4);
  u16* wqkvt = (u16*)alloc(3 * 16384 * 2);
  u16* wot   = (u16*)alloc(16384 * 2);
  u16* w1t   = (u16*)alloc(65536 * 2);
  u16* w2t   = (u16*)alloc(65536 * 2);

  prep_k<<<768 + NTOK / 2, 256, 0, stream>>>(
      w1, w2, wq, wk, wv, wo, x, w1t, w2t, wqkvt, wot, xg);
  qkv_gemm_k<0><<<dim3(NTOK / 64, 6), 256, 0, stream>>>(xg, wqkvt, bq, bk, bv, qw, kw, vtw);
  win_attn_k<<<256, 256, 0, stream>>>(qw, kw, vtw, aow);
  proj_ln_k<0><<<NTOK / 64, 256, 0, stream>>>(
      aow, nullptr, nullptr, wot, bo, nullptr, g1, be1, xf, xg);
  qkv_gemm_k<1><<<dim3(NTOK / 64, 6), 256, 0, stream>>>(xg, wqkvt, bq, bk, bv, qw, kw, vtw);
  glb_attn_k<<<1568, 128, 0, stream>>>(qw, kw, vtw, po, pl);
  proj_ln_k<1><<<NTOK / 64, 256, 0, stream>>>(
      nullptr, po, pl, wot, bo, xf, g2, be2, xf, xg);
  gemm1_k<<<dim3(NTOK / 64, 8), 256, 0, stream>>>(xg, w1t, b1, hb);
  gemm2_k<<<dim3(NTOK / 64, 2), 256, 0, stream>>>(hb, w2t, b2, xf, out);
}

// Round 14
// 113.964 us; speedup vs baseline: 1.0504x; 1.0504x over previous
//
#include <hip/hip_runtime.h>
#include <hip/hip_bf16.h>
#include <math.h>

#define NH 4
#define DK 32
#define CC 128
#define HW 56
#define SHIFT 3
#define NTOK 12544   // 4*56*56 == 256*49
#define S_GLB 3136
#define VTW_STRIDE 12608
#define SCALE_L2E 0.25503488f  // log2(e)/sqrt(32): exp2-domain softmax scale

typedef unsigned short u16;
typedef short bf16x8 __attribute__((ext_vector_type(8)));
typedef unsigned short u16x8 __attribute__((ext_vector_type(8)));
typedef float f32x4 __attribute__((ext_vector_type(4)));

static __device__ __forceinline__ u16 f2bf(float f) {
  unsigned int b = __builtin_bit_cast(unsigned int, f);
  return (u16)((b + 0x7FFFu + ((b >> 16) & 1u)) >> 16);
}
static __device__ __forceinline__ unsigned pk2bf(float a, float b) {
  unsigned r;
  asm("v_cvt_pk_bf16_f32 %0, %1, %2" : "=v"(r) : "v"(a), "v"(b));
  return r;
}
static __device__ __forceinline__ float fexp2(float x) {
  float r;
  asm("v_exp_f32 %0, %1" : "=v"(r) : "v"(x));
  return r;
}
static __device__ __forceinline__ void gload16(const void* g, void* l) {
  __builtin_amdgcn_global_load_lds(
      (const __attribute__((address_space(1))) unsigned int*)g,
      (__attribute__((address_space(3))) unsigned int*)l, 16, 0, 0);
}

// ---------------- prep: weight converts (blocks 0..767) + shift-gather (rest)
__global__ __launch_bounds__(256) void prep_k(
    const float* __restrict__ w1, const float* __restrict__ w2,
    const float* __restrict__ wq, const float* __restrict__ wk,
    const float* __restrict__ wv, const float* __restrict__ wo,
    const float* __restrict__ x,
    u16* __restrict__ w1t, u16* __restrict__ w2t,
    u16* __restrict__ wqkvt, u16* __restrict__ wot, u16* __restrict__ xg) {
  if (blockIdx.x < 768) {
    const int idx = blockIdx.x * 256 + threadIdx.x;
    if (idx < 65536) {            // w1 [128][512] -> w1t [512][128]
      const int c = idx >> 7, r = idx & 127;
      w1t[idx] = f2bf(w1[r * 512 + c]);
    } else if (idx < 131072) {    // w2 [512][128] -> w2t [128][512]
      const int o = idx - 65536;
      const int c = o / 512, r = o - c * 512;
      w2t[o] = f2bf(w2[r * 128 + c]);
    } else {                      // four 128x128 -> transposed
      const int o = idx - 131072;
      const int which = o >> 14, oo = o & 16383;
      const int c = oo >> 7, r = oo & 127;
      const float* src = (which == 0) ? wq : (which == 1) ? wk : (which == 2) ? wv : wo;
      u16* dst = (which < 3) ? (wqkvt + which * 16384) : wot;
      dst[oo] = f2bf(src[r * 128 + c]);
    }
  } else {
    const int bid = blockIdx.x - 768;
    const int t = bid * 2 + (threadIdx.x >> 7);
    const int c = threadIdx.x & 127;
    const int win = t / 49, tok = t % 49;
    const int b = win >> 6, wrem = win & 63;
    const int wi = wrem >> 3, wj = wrem & 7;
    const int i = tok / 7, j = tok % 7;
    int hh = wi * 7 + i + SHIFT; if (hh >= HW) hh -= HW;
    int ww = wj * 7 + j + SHIFT; if (ww >= HW) ww -= HW;
    xg[(size_t)t * CC + c] = f2bf(x[((size_t)(b * HW + hh) * HW + ww) * CC + c]);
  }
}

// ---------------- fused QKV GEMM. y = widx (0=q,1=k,2=v); xs staged ONCE,
// two n-halves looped internally (weight half re-staged, x not).
template <int PATH>
__global__ __launch_bounds__(256) void qkv_gemm_k(
    const u16* __restrict__ xin, const u16* __restrict__ wqkvt,
    const float* __restrict__ bq, const float* __restrict__ bk,
    const float* __restrict__ bv,
    u16* __restrict__ qo, u16* __restrict__ ko, u16* __restrict__ vto) {
  __shared__ __align__(16) u16 xs[64][136];
  __shared__ __align__(16) u16 wt[64][136];
  const int tid = threadIdx.x;
  const int w = tid >> 6, lane = tid & 63;
  const int lo = lane & 15, hi = lane >> 4, hi4 = hi * 4;
  const int m0 = blockIdx.x * 64;
  const int widx = blockIdx.y;
  const int rS = tid >> 2, sgS = tid & 3;
  {
    const u16* sx = &xin[(size_t)(m0 + rS) * CC + sgS * 32];
#pragma unroll
    for (int j = 0; j < 4; ++j)
      *reinterpret_cast<u16x8*>(&xs[rS][sgS * 32 + j * 8]) = *reinterpret_cast<const u16x8*>(&sx[j * 8]);
  }
  for (int half = 0; half < 2; ++half) {
    const int n0 = half * 64;
    if (half) __syncthreads();  // all reads of wt(half0) done
    {
      const u16* sw = &wqkvt[(size_t)widx * CC * CC + (size_t)(n0 + rS) * CC + sgS * 32];
#pragma unroll
      for (int j = 0; j < 4; ++j)
        *reinterpret_cast<u16x8*>(&wt[rS][sgS * 32 + j * 8]) = *reinterpret_cast<const u16x8*>(&sw[j * 8]);
    }
    __syncthreads();
    if (widx < 2) {
      const float* bias = (widx == 0) ? bq : bk;
      u16* outp = (widx == 0) ? qo : ko;
      const float oscale = (widx == 0) ? SCALE_L2E : 1.0f;
      f32x4 acc[4];
#pragma unroll
      for (int st = 0; st < 4; ++st) {
        const float b_ = bias[n0 + st * 16 + lo];
        acc[st] = (f32x4){b_, b_, b_, b_};
      }
#pragma unroll
      for (int kk = 0; kk < 4; ++kk) {
        const bf16x8 af = *reinterpret_cast<const bf16x8*>(&xs[w * 16 + lo][kk * 32 + 8 * hi]);
#pragma unroll
        for (int st = 0; st < 4; ++st) {
          const bf16x8 bfr = *reinterpret_cast<const bf16x8*>(&wt[st * 16 + lo][kk * 32 + 8 * hi]);
          acc[st] = __builtin_amdgcn_mfma_f32_16x16x32_bf16(af, bfr, acc[st], 0, 0, 0);
        }
      }
#pragma unroll
      for (int r = 0; r < 4; ++r) {
        const int mm = m0 + w * 16 + hi4 + r;
        size_t rowbase, hstride;
        if (PATH == 0) {
          const int win = mm / 49, tok = mm - win * 49;
          rowbase = ((size_t)(win * 4) * 49 + tok) * DK;
          hstride = (size_t)49 * DK;
        } else {
          const int b = mm / S_GLB, s = mm - b * S_GLB;
          rowbase = ((size_t)(b * 4) * S_GLB + s) * DK;
          hstride = (size_t)S_GLB * DK;
        }
#pragma unroll
        for (int st = 0; st < 4; ++st) {
          const int c = n0 + st * 16 + lo, h = c >> 5, d = c & 31;
          outp[rowbase + (size_t)h * hstride + d] = f2bf(acc[st][r] * oscale);
        }
      }
    } else {
      f32x4 bias4;
#pragma unroll
      for (int r = 0; r < 4; ++r) bias4[r] = bv[n0 + w * 16 + hi4 + r];
      f32x4 acc[4];
#pragma unroll
      for (int st = 0; st < 4; ++st) acc[st] = bias4;
#pragma unroll
      for (int kk = 0; kk < 4; ++kk) {
        const bf16x8 af = *reinterpret_cast<const bf16x8*>(&wt[w * 16 + lo][kk * 32 + 8 * hi]);
#pragma unroll
        for (int st = 0; st < 4; ++st) {
          const bf16x8 bfr = *reinterpret_cast<const bf16x8*>(&xs[st * 16 + lo][kk * 32 + 8 * hi]);
          acc[st] = __builtin_amdgcn_mfma_f32_16x16x32_bf16(af, bfr, acc[st], 0, 0, 0);
        }
      }
#pragma unroll
      for (int st = 0; st < 4; ++st) {
        const int mm = m0 + st * 16 + lo;
#pragma unroll
        for (int r = 0; r < 4; ++r) {
          const int c = n0 + w * 16 + hi4 + r;
          if (PATH == 0) {
            vto[(size_t)c * VTW_STRIDE + mm] = f2bf(acc[st][r]);
          } else {
            const int b = mm / S_GLB, s = mm - b * S_GLB;
            vto[((size_t)b * CC + c) * S_GLB + s] = f2bf(acc[st][r]);
          }
        }
      }
    }
  }
}

// ---------------- window attention: no-max exp2 softmax, l via ones-MFMA
__global__ __launch_bounds__(256) void win_attn_k(
    const u16* __restrict__ qw, const u16* __restrict__ kw,
    const u16* __restrict__ vtw, u16* __restrict__ aow) {
  __shared__ __align__(16) u16 psh[4][16][72];
  const int tid = threadIdx.x;
  const int wvi = tid >> 6, lane = tid & 63;
  const int lo = lane & 15, hi = lane >> 4, hi4 = hi * 4;
  const int wh = blockIdx.x * 4 + wvi;
  const int win = wh >> 2, hd = wh & 3;
  const f32x4 zero4 = {0.f, 0.f, 0.f, 0.f};
  bf16x8 ones;
#pragma unroll
  for (int j = 0; j < 8; ++j) ones[j] = (short)0x3F80;

  bf16x8 kf[4], vf[2][2];
#pragma unroll
  for (int st = 0; st < 4; ++st)
    kf[st] = *reinterpret_cast<const bf16x8*>(&kw[((size_t)wh * 49 + st * 16 + lo) * DK + 8 * hi]);
#pragma unroll
  for (int dst = 0; dst < 2; ++dst)
#pragma unroll
    for (int kch = 0; kch < 2; ++kch)
      vf[dst][kch] = *reinterpret_cast<const bf16x8*>(
          &vtw[(size_t)(hd * DK + dst * 16 + lo) * VTW_STRIDE + win * 49 + kch * 32 + 8 * hi]);

#pragma unroll
  for (int g = 0; g < 4; ++g) {
    const bf16x8 qf = *reinterpret_cast<const bf16x8*>(
        &qw[((size_t)wh * 49 + g * 16 + lo) * DK + 8 * hi]);
    f32x4 s4[4];
#pragma unroll
    for (int st = 0; st < 4; ++st) {
      s4[st] = __builtin_amdgcn_mfma_f32_16x16x32_bf16(kf[st], qf, zero4, 0, 0, 0);
#pragma unroll
      for (int r = 0; r < 4; ++r)
        if (st * 16 + hi4 + r >= 49) s4[st][r] = -1e30f;  // mask pad keys -> p=0
    }
#pragma unroll
    for (int st = 0; st < 4; ++st) {
      uint2 pk;
      pk.x = pk2bf(fexp2(s4[st][0]), fexp2(s4[st][1]));
      pk.y = pk2bf(fexp2(s4[st][2]), fexp2(s4[st][3]));
      *reinterpret_cast<uint2*>(&psh[wvi][lo][st * 16 + hi4]) = pk;
    }
    asm volatile("" ::: "memory");
    f32x4 acc0 = zero4, acc1 = zero4, lacc = zero4;
#pragma unroll
    for (int kch = 0; kch < 2; ++kch) {
      const bf16x8 pa = *reinterpret_cast<const bf16x8*>(&psh[wvi][lo][kch * 32 + 8 * hi]);
      acc0 = __builtin_amdgcn_mfma_f32_16x16x32_bf16(pa, vf[0][kch], acc0, 0, 0, 0);
      acc1 = __builtin_amdgcn_mfma_f32_16x16x32_bf16(pa, vf[1][kch], acc1, 0, 0, 0);
      lacc = __builtin_amdgcn_mfma_f32_16x16x32_bf16(pa, ones, lacc, 0, 0, 0);
    }
#pragma unroll
    for (int r = 0; r < 4; ++r) {
      const int qrow = g * 16 + hi4 + r;
      if (qrow < 49) {
        const float rl = 1.0f / lacc[r];
        const size_t tw = (size_t)win * 49 + qrow;
        aow[tw * CC + hd * DK + lo] = f2bf(acc0[r] * rl);
        aow[tw * CC + hd * DK + 16 + lo] = f2bf(acc1[r] * rl);
      }
    }
  }
}

// ---------------- global attention: split-K, 4-wave 2-buffer 2-phase,
// XCD-bijective swizzle. (R12 body — proven 49.4 us.)
__global__ __launch_bounds__(256) void glb_attn_k(
    const u16* __restrict__ qg, const u16* __restrict__ kg,
    const u16* __restrict__ vtg, float* __restrict__ po, float* __restrict__ pl) {
  __shared__ __align__(16) u16 ksh[2][64][32];   // linear, conflict-free reads
  __shared__ __align__(16) u16 vtsh[2][32][64];  // content XOR-swizzled via source
  __shared__ __align__(16) u16 psh[4][16][64];   // XOR-swizzled write/read
  const int tid = threadIdx.x;
  const int w = tid >> 6, lane = tid & 63;
  const int lo = lane & 15, hi = lane >> 4, hi4 = hi * 4;
  // XCD-bijective swizzle: 1568 blocks = 8 XCDs x 196.
  const int wg = blockIdx.x;
  const int sid = (wg & 7) * 196 + (wg >> 3);
  const int sp = sid / 784;
  const int rem = sid - sp * 784;
  const int bh = rem / 49;
  const int q0 = (rem - bh * 49) * 64;
  const int kt_beg = sp * 25;
  const int kt_end = sp ? 49 : 25;
  const f32x4 zero4 = {0.f, 0.f, 0.f, 0.f};
  bf16x8 ones;
#pragma unroll
  for (int j = 0; j < 8; ++j) ones[j] = (short)0x3F80;

  const bf16x8 qfrag = *reinterpret_cast<const bf16x8*>(
      &qg[((size_t)bh * S_GLB + q0 + w * 16 + lo) * DK + 8 * hi]);
  const u16* kg0 = kg + (size_t)bh * S_GLB * DK;
  const u16* vg0 = vtg + (size_t)bh * DK * S_GLB;

  const u16* ksrc = kg0 + (size_t)(w * 16 + (lane >> 2)) * DK + (lane & 3) * 8;
  const u16* vsrc = vg0 + (size_t)(w * 8 + (lane >> 3)) * S_GLB + ((lane & 7) ^ (lane >> 3)) * 8;
  u16* kdst0 = &ksh[0][w * 16][0]; u16* kdst1 = &ksh[1][w * 16][0];
  u16* vdst0 = &vtsh[0][w * 8][0]; u16* vdst1 = &vtsh[1][w * 8][0];

  f32x4 oacc0 = zero4, oacc1 = zero4, lacc = zero4;

  gload16(ksrc + (size_t)kt_beg * 64 * DK, kdst0);
  gload16(vsrc + (size_t)kt_beg * 64, vdst0);
  __syncthreads();

  char* const pbase = (char*)&psh[w][lo][0];
  char* const vbase0 = (char*)&vtsh[0][0][0];
  const unsigned swz = (unsigned)(lo & 7) << 4;

  for (int kt = kt_beg; kt < kt_end; ++kt) {
    const int cur = (kt - kt_beg) & 1;
    if (kt + 1 < kt_end) {  // issue next-tile DMA before compute (2-phase)
      gload16(ksrc + (size_t)(kt + 1) * 64 * DK, cur ? kdst0 : kdst1);
      gload16(vsrc + (size_t)(kt + 1) * 64, cur ? vdst0 : vdst1);
    }
    // S^T = K * Q^T
    f32x4 s4[4];
#pragma unroll
    for (int st = 0; st < 4; ++st) {
      const bf16x8 kfrag = *reinterpret_cast<const bf16x8*>(&ksh[cur][st * 16 + lo][8 * hi]);
      s4[st] = __builtin_amdgcn_mfma_f32_16x16x32_bf16(kfrag, qfrag, zero4, 0, 0, 0);
    }
    // p = exp2(s), pack to bf16, swizzled P store
#pragma unroll
    for (int st = 0; st < 4; ++st) {
      uint2 pk;
      pk.x = pk2bf(fexp2(s4[st][0]), fexp2(s4[st][1]));
      pk.y = pk2bf(fexp2(s4[st][2]), fexp2(s4[st][3]));
      *reinterpret_cast<uint2*>(pbase + (((unsigned)(st * 32 + hi * 8)) ^ swz)) = pk;
    }
    asm volatile("" ::: "memory");
    // PV + l via ones-MFMA
    char* const vrow0 = vbase0 + (size_t)cur * (32 * 64 * 2) + lo * 128;
#pragma unroll
    for (int kch = 0; kch < 2; ++kch) {
      const unsigned off = ((unsigned)(kch * 64 + hi * 16)) ^ swz;
      const bf16x8 pa = *reinterpret_cast<const bf16x8*>(pbase + off);
      const bf16x8 v0 = *reinterpret_cast<const bf16x8*>(vrow0 + off);
      const bf16x8 v1 = *reinterpret_cast<const bf16x8*>(vrow0 + 16 * 128 + off);
      oacc0 = __builtin_amdgcn_mfma_f32_16x16x32_bf16(pa, v0, oacc0, 0, 0, 0);
      oacc1 = __builtin_amdgcn_mfma_f32_16x16x32_bf16(pa, v1, oacc1, 0, 0, 0);
      lacc = __builtin_amdgcn_mfma_f32_16x16x32_bf16(pa, ones, lacc, 0, 0, 0);
    }
    __syncthreads();  // drains vmcnt: next tile landed; cur free to overwrite
  }

  const int b = bh >> 2, hd = bh & 3;
  float* pob = po + (size_t)sp * NTOK * CC;
#pragma unroll
  for (int r = 0; r < 4; ++r) {
    const size_t t = (size_t)b * S_GLB + q0 + w * 16 + hi4 + r;
    pob[t * CC + hd * DK + lo] = oacc0[r];
    pob[t * CC + hd * DK + 16 + lo] = oacc1[r];
    if (lo == 0)
      pl[((size_t)sp * 16 + bh) * S_GLB + q0 + w * 16 + hi4 + r] = lacc[r];
  }
}

// ---------------- output projection GEMM with FUSED LayerNorm epilogue.
template <int MODE>
__global__ __launch_bounds__(256) void proj_ln_k(
    const u16* __restrict__ ain, const float* __restrict__ po,
    const float* __restrict__ pl, const u16* __restrict__ wot,
    const float* __restrict__ bo, const float* __restrict__ resid,
    const float* __restrict__ lng, const float* __restrict__ lnb,
    float* __restrict__ xfo, u16* __restrict__ ybf) {
  __shared__ __align__(16) u16 xs[64][136];
  __shared__ __align__(16) u16 wt[128][136];
  const int tid = threadIdx.x;
  const int w = tid >> 6, lane = tid & 63;
  const int lo = lane & 15, hi = lane >> 4, hi4 = hi * 4;
  const int m0 = blockIdx.x * 64;
  {
    const int r = tid >> 2, sg = tid & 3;
    if (MODE == 0) {
      const u16* sx = &ain[(size_t)(m0 + r) * CC + sg * 32];
#pragma unroll
      for (int j = 0; j < 4; ++j)
        *reinterpret_cast<u16x8*>(&xs[r][sg * 32 + j * 8]) = *reinterpret_cast<const u16x8*>(&sx[j * 8]);
    } else {
      // fused split-K combine: head == sg (32 channels/head)
      const int mm = m0 + r;
      const int b = mm / S_GLB, s_ = mm - b * S_GLB;
      const float l0 = pl[((size_t)(b * 4 + sg)) * S_GLB + s_];
      const float l1 = pl[((size_t)(16 + b * 4 + sg)) * S_GLB + s_];
      const float rl = 1.0f / (l0 + l1);
      const float* pa = &po[(size_t)mm * CC + sg * 32];
      const float* pb = pa + (size_t)NTOK * CC;
#pragma unroll
      for (int j = 0; j < 32; j += 4) {
        const float4 a4 = *reinterpret_cast<const float4*>(&pa[j]);
        const float4 b4 = *reinterpret_cast<const float4*>(&pb[j]);
        uint2 pk;
        pk.x = pk2bf((a4.x + b4.x) * rl, (a4.y + b4.y) * rl);
        pk.y = pk2bf((a4.z + b4.z) * rl, (a4.w + b4.w) * rl);
        *reinterpret_cast<uint2*>(&xs[r][sg * 32 + j]) = pk;
      }
    }
    // weights: 128 rows x 128 cols
    const int r2 = tid >> 1, sg2 = tid & 1;
    const u16* sw = &wot[(size_t)r2 * CC + sg2 * 64];
#pragma unroll
    for (int j = 0; j < 8; ++j)
      *reinterpret_cast<u16x8*>(&wt[r2][sg2 * 64 + j * 8]) = *reinterpret_cast<const u16x8*>(&sw[j * 8]);
  }
  __syncthreads();
  f32x4 acc[8];
#pragma unroll
  for (int st = 0; st < 8; ++st) {
    const float b_ = bo[st * 16 + lo];
    acc[st] = (f32x4){b_, b_, b_, b_};
  }
#pragma unroll
  for (int kk = 0; kk < 4; ++kk) {
    const bf16x8 af = *reinterpret_cast<const bf16x8*>(&xs[w * 16 + lo][kk * 32 + 8 * hi]);
#pragma unroll
    for (int st = 0; st < 8; ++st) {
      const bf16x8 bfr = *reinterpret_cast<const bf16x8*>(&wt[st * 16 + lo][kk * 32 + 8 * hi]);
      acc[st] = __builtin_amdgcn_mfma_f32_16x16x32_bf16(af, bfr, acc[st], 0, 0, 0);
    }
  }
  float gv[8], bv2[8];
#pragma unroll
  for (int st = 0; st < 8; ++st) { gv[st] = lng[st * 16 + lo]; bv2[st] = lnb[st * 16 + lo]; }
#pragma unroll
  for (int r = 0; r < 4; ++r) {
    const int mm = m0 + w * 16 + hi4 + r;
    size_t trow;
    if (MODE == 0) {
      const int win = mm / 49, tok = mm - win * 49;
      const int b = win >> 6, wi = (win >> 3) & 7, wj = win & 7;
      const int ii = tok / 7, jj = tok - ii * 7;
      int hr = wi * 7 + ii + SHIFT; if (hr >= HW) hr -= HW;
      int wr = wj * 7 + jj + SHIFT; if (wr >= HW) wr -= HW;
      trow = (size_t)b * S_GLB + hr * HW + wr;
    } else {
      trow = (size_t)mm;
    }
    float v[8];
    float s = 0.f, sq = 0.f;
#pragma unroll
    for (int st = 0; st < 8; ++st) {
      float t_ = acc[st][r];
      if (MODE == 1) t_ += resid[trow * CC + st * 16 + lo];
      v[st] = t_;
      s += t_;
      sq += t_ * t_;
    }
    s += __shfl_xor(s, 1); s += __shfl_xor(s, 2); s += __shfl_xor(s, 4); s += __shfl_xor(s, 8);
    sq += __shfl_xor(sq, 1); sq += __shfl_xor(sq, 2); sq += __shfl_xor(sq, 4); sq += __shfl_xor(sq, 8);
    const float mu = s * 0.0078125f;
    const float rsig = rsqrtf(sq * 0.0078125f - mu * mu + 1e-5f);
#pragma unroll
    for (int st = 0; st < 8; ++st) {
      const size_t idx = trow * CC + st * 16 + lo;
      xfo[idx] = v[st];
      ybf[idx] = f2bf((v[st] - mu) * rsig * gv[st] + bv2[st]);
    }
  }
}

// ---------------- GEMM1 [NTOK,128]@[128,512] + gelu -> bf16
__global__ __launch_bounds__(256) void gemm1_k(
    const u16* __restrict__ ybf, const u16* __restrict__ w1t,
    const float* __restrict__ b1, u16* __restrict__ hb) {
  __shared__ __align__(16) u16 xs[64][136];
  __shared__ __align__(16) u16 wt[64][136];
  const int tid = threadIdx.x;
  const int w = tid >> 6, lane = tid & 63;
  const int lo = lane & 15, hi = lane >> 4;
  const int m0 = blockIdx.x * 64, n0 = blockIdx.y * 64;
  {
    const int r = tid >> 2, sg = tid & 3;
    const u16* src_x = &ybf[(size_t)(m0 + r) * CC + sg * 32];
    const u16* src_w = &w1t[(size_t)(n0 + r) * CC + sg * 32];
#pragma unroll
    for (int j = 0; j < 4; ++j) {
      *reinterpret_cast<u16x8*>(&xs[r][sg * 32 + j * 8]) = *reinterpret_cast<const u16x8*>(&src_x[j * 8]);
      *reinterpret_cast<u16x8*>(&wt[r][sg * 32 + j * 8]) = *reinterpret_cast<const u16x8*>(&src_w[j * 8]);
    }
  }
  __syncthreads();
  f32x4 acc[4];
#pragma unroll
  for (int st = 0; st < 4; ++st) {
    const float bv = b1[n0 + st * 16 + lo];
    acc[st] = (f32x4){bv, bv, bv, bv};
  }
#pragma unroll
  for (int kk = 0; kk < 4; ++kk) {
    const bf16x8 af = *reinterpret_cast<const bf16x8*>(&xs[w * 16 + lo][kk * 32 + 8 * hi]);
#pragma unroll
    for (int st = 0; st < 4; ++st) {
      const bf16x8 bfr = *reinterpret_cast<const bf16x8*>(&wt[st * 16 + lo][kk * 32 + 8 * hi]);
      acc[st] = __builtin_amdgcn_mfma_f32_16x16x32_bf16(af, bfr, acc[st], 0, 0, 0);
    }
  }
#pragma unroll
  for (int st = 0; st < 4; ++st) {
#pragma unroll
    for (int r = 0; r < 4; ++r) {
      const float val = acc[st][r];
      const float gel = 0.5f * val * (1.0f + erff(val * 0.70710678118f));
      hb[(size_t)(m0 + w * 16 + (hi << 2) + r) * 512 + n0 + st * 16 + lo] = f2bf(gel);
    }
  }
}

// ---------------- GEMM2 [NTOK,512]@[512,128] + residual -> out
__global__ __launch_bounds__(256) void gemm2_k(
    const u16* __restrict__ hb, const u16* __restrict__ w2t,
    const float* __restrict__ b2, const float* __restrict__ xf,
    float* __restrict__ out) {
  __shared__ __align__(16) u16 xs[64][136];
  __shared__ __align__(16) u16 wt[64][136];
  const int tid = threadIdx.x;
  const int w = tid >> 6, lane = tid & 63;
  const int lo = lane & 15, hi = lane >> 4;
  const int m0 = blockIdx.x * 64, n0 = blockIdx.y * 64;
  f32x4 acc[4];
#pragma unroll
  for (int st = 0; st < 4; ++st) {
    const float bv = b2[n0 + st * 16 + lo];
    acc[st] = (f32x4){bv, bv, bv, bv};
  }
  for (int kc = 0; kc < 4; ++kc) {
    if (kc) __syncthreads();
    {
      const int r = tid >> 2, sg = tid & 3;
      const u16* src_x = &hb[(size_t)(m0 + r) * 512 + kc * 128 + sg * 32];
      const u16* src_w = &w2t[(size_t)(n0 + r) * 512 + kc * 128 + sg * 32];
#pragma unroll
      for (int j = 0; j < 4; ++j) {
        *reinterpret_cast<u16x8*>(&xs[r][sg * 32 + j * 8]) = *reinterpret_cast<const u16x8*>(&src_x[j * 8]);
        *reinterpret_cast<u16x8*>(&wt[r][sg * 32 + j * 8]) = *reinterpret_cast<const u16x8*>(&src_w[j * 8]);
      }
    }
    __syncthreads();
#pragma unroll
    for (int kk = 0; kk < 4; ++kk) {
      const bf16x8 af = *reinterpret_cast<const bf16x8*>(&xs[w * 16 + lo][kk * 32 + 8 * hi]);
#pragma unroll
      for (int st = 0; st < 4; ++st) {
        const bf16x8 bfr = *reinterpret_cast<const bf16x8*>(&wt[st * 16 + lo][kk * 32 + 8 * hi]);
        acc[st] = __builtin_amdgcn_mfma_f32_16x16x32_bf16(af, bfr, acc[st], 0, 0, 0);
      }
    }
  }
#pragma unroll
  for (int st = 0; st < 4; ++st) {
#pragma unroll
    for (int r = 0; r < 4; ++r) {
      const size_t idx = (size_t)(m0 + w * 16 + (hi << 2) + r) * CC + n0 + st * 16 + lo;
      out[idx] = xf[idx] + acc[st][r];
    }
  }
}

extern "C" void kernel_launch(void* const* d_in, const int* in_sizes, int n_in,
                              void* d_out, int out_size, void* d_ws, size_t ws_size,
                              hipStream_t stream) {
  (void)in_sizes; (void)n_in; (void)out_size; (void)ws_size;
  const float* x   = (const float*)d_in[0];
  const float* wq  = (const float*)d_in[1];
  const float* bq  = (const float*)d_in[2];
  const float* wk  = (const float*)d_in[3];
  const float* bk  = (const float*)d_in[4];
  const float* wv  = (const float*)d_in[5];
  const float* bv  = (const float*)d_in[6];
  const float* wo  = (const float*)d_in[7];
  const float* bo  = (const float*)d_in[8];
  const float* w1  = (const float*)d_in[9];
  const float* b1  = (const float*)d_in[10];
  const float* w2  = (const float*)d_in[11];
  const float* b2  = (const float*)d_in[12];
  const float* g1  = (const float*)d_in[13];
  const float* be1 = (const float*)d_in[14];
  const float* g2  = (const float*)d_in[15];
  const float* be2 = (const float*)d_in[16];
  float* out = (float*)d_out;

  char* p = (char*)d_ws;
  auto alloc = [&](size_t bytes) { char* r = p; p += (bytes + 255) & ~(size_t)255; return r; };
  float* xf  = (float*)alloc((size_t)NTOK * CC * 4);
  u16* xg    = (u16*)alloc((size_t)NTOK * CC * 2);   // gather out / LN out (ybf)
  u16* qw    = (u16*)alloc((size_t)NTOK * CC * 2 + 4096);
  u16* kw    = (u16*)alloc((size_t)NTOK * CC * 2 + 4096);
  u16* vtw   = (u16*)alloc((size_t)CC * VTW_STRIDE * 2);
  u16* aow   = (u16*)alloc((size_t)NTOK * CC * 2);
  u16* hb    = (u16*)alloc((size_t)NTOK * 512 * 2);
  float* po  = (float*)alloc((size_t)2 * NTOK * CC * 4);
  float* pl  = (float*)alloc((size_t)2 * 16 * S_GLB * 4);
  u16* wqkvt = (u16*)alloc(3 * 16384 * 2);
  u16* wot   = (u16*)alloc(16384 * 2);
  u16* w1t   = (u16*)alloc(65536 * 2);
  u16* w2t   = (u16*)alloc(65536 * 2);

  prep_k<<<768 + NTOK / 2, 256, 0, stream>>>(
      w1, w2, wq, wk, wv, wo, x, w1t, w2t, wqkvt, wot, xg);
  qkv_gemm_k<0><<<dim3(NTOK / 64, 3), 256, 0, stream>>>(xg, wqkvt, bq, bk, bv, qw, kw, vtw);
  win_attn_k<<<256, 256, 0, stream>>>(qw, kw, vtw, aow);
  proj_ln_k<0><<<NTOK / 64, 256, 0, stream>>>(
      aow, nullptr, nullptr, wot, bo, nullptr, g1, be1, xf, xg);
  qkv_gemm_k<1><<<dim3(NTOK / 64, 3), 256, 0, stream>>>(xg, wqkvt, bq, bk, bv, qw, kw, vtw);
  glb_attn_k<<<1568, 256, 0, stream>>>(qw, kw, vtw, po, pl);
  proj_ln_k<1><<<NTOK / 64, 256, 0, stream>>>(
      nullptr, po, pl, wot, bo, xf, g2, be2, xf, xg);
  gemm1_k<<<dim3(NTOK / 64, 8), 256, 0, stream>>>(xg, w1t, b1, hb);
  gemm2_k<<<dim3(NTOK / 64, 2), 256, 0, stream>>>(hb, w2t, b2, xf, out);
}

// Round 15
// 111.372 us; speedup vs baseline: 1.0749x; 1.0233x over previous
//
#include <hip/hip_runtime.h>
#include <hip/hip_bf16.h>
#include <math.h>

#define NH 4
#define DK 32
#define CC 128
#define HW 56
#define SHIFT 3
#define NTOK 12544   // 4*56*56 == 256*49
#define S_GLB 3136
#define VTW_STRIDE 12608
#define SCALE_L2E 0.25503488f  // log2(e)/sqrt(32): exp2-domain softmax scale

typedef unsigned short u16;
typedef short bf16x8 __attribute__((ext_vector_type(8)));
typedef unsigned short u16x8 __attribute__((ext_vector_type(8)));
typedef float f32x4 __attribute__((ext_vector_type(4)));

static __device__ __forceinline__ u16 f2bf(float f) {
  unsigned int b = __builtin_bit_cast(unsigned int, f);
  return (u16)((b + 0x7FFFu + ((b >> 16) & 1u)) >> 16);
}
static __device__ __forceinline__ float bf2f(u16 v) {
  unsigned int b = (unsigned int)v << 16;
  return __builtin_bit_cast(float, b);
}
static __device__ __forceinline__ unsigned pk2bf(float a, float b) {
  unsigned r;
  asm("v_cvt_pk_bf16_f32 %0, %1, %2" : "=v"(r) : "v"(a), "v"(b));
  return r;
}
static __device__ __forceinline__ float fexp2(float x) {
  float r;
  asm("v_exp_f32 %0, %1" : "=v"(r) : "v"(x));
  return r;
}
static __device__ __forceinline__ void gload16(const void* g, void* l) {
  __builtin_amdgcn_global_load_lds(
      (const __attribute__((address_space(1))) unsigned int*)g,
      (__attribute__((address_space(3))) unsigned int*)l, 16, 0, 0);
}

// ---------------- prep: weight converts (blocks 0..767) + shift-gather (rest)
__global__ __launch_bounds__(256) void prep_k(
    const float* __restrict__ w1, const float* __restrict__ w2,
    const float* __restrict__ wq, const float* __restrict__ wk,
    const float* __restrict__ wv, const float* __restrict__ wo,
    const float* __restrict__ x,
    u16* __restrict__ w1t, u16* __restrict__ w2t,
    u16* __restrict__ wqkvt, u16* __restrict__ wot, u16* __restrict__ xg) {
  if (blockIdx.x < 768) {
    const int idx = blockIdx.x * 256 + threadIdx.x;
    if (idx < 65536) {            // w1 [128][512] -> w1t [512][128]
      const int c = idx >> 7, r = idx & 127;
      w1t[idx] = f2bf(w1[r * 512 + c]);
    } else if (idx < 131072) {    // w2 [512][128] -> w2t [128][512]
      const int o = idx - 65536;
      const int c = o / 512, r = o - c * 512;
      w2t[o] = f2bf(w2[r * 128 + c]);
    } else {                      // four 128x128 -> transposed
      const int o = idx - 131072;
      const int which = o >> 14, oo = o & 16383;
      const int c = oo >> 7, r = oo & 127;
      const float* src = (which == 0) ? wq : (which == 1) ? wk : (which == 2) ? wv : wo;
      u16* dst = (which < 3) ? (wqkvt + which * 16384) : wot;
      dst[oo] = f2bf(src[r * 128 + c]);
    }
  } else {
    const int bid = blockIdx.x - 768;
    const int t = bid * 2 + (threadIdx.x >> 7);
    const int c = threadIdx.x & 127;
    const int win = t / 49, tok = t % 49;
    const int b = win >> 6, wrem = win & 63;
    const int wi = wrem >> 3, wj = wrem & 7;
    const int i = tok / 7, j = tok % 7;
    int hh = wi * 7 + i + SHIFT; if (hh >= HW) hh -= HW;
    int ww = wj * 7 + j + SHIFT; if (ww >= HW) ww -= HW;
    xg[(size_t)t * CC + c] = f2bf(x[((size_t)(b * HW + hh) * HW + ww) * CC + c]);
  }
}

// ---------------- fused QKV GEMM. y = widx (0=q,1=k,2=v); xs staged ONCE,
// two n-halves looped internally (weight half re-staged, x not).
template <int PATH>
__global__ __launch_bounds__(256) void qkv_gemm_k(
    const u16* __restrict__ xin, const u16* __restrict__ wqkvt,
    const float* __restrict__ bq, const float* __restrict__ bk,
    const float* __restrict__ bv,
    u16* __restrict__ qo, u16* __restrict__ ko, u16* __restrict__ vto) {
  __shared__ __align__(16) u16 xs[64][136];
  __shared__ __align__(16) u16 wt[64][136];
  const int tid = threadIdx.x;
  const int w = tid >> 6, lane = tid & 63;
  const int lo = lane & 15, hi = lane >> 4, hi4 = hi * 4;
  const int m0 = blockIdx.x * 64;
  const int widx = blockIdx.y;
  const int rS = tid >> 2, sgS = tid & 3;
  {
    const u16* sx = &xin[(size_t)(m0 + rS) * CC + sgS * 32];
#pragma unroll
    for (int j = 0; j < 4; ++j)
      *reinterpret_cast<u16x8*>(&xs[rS][sgS * 32 + j * 8]) = *reinterpret_cast<const u16x8*>(&sx[j * 8]);
  }
  for (int half = 0; half < 2; ++half) {
    const int n0 = half * 64;
    if (half) __syncthreads();  // all reads of wt(half0) done
    {
      const u16* sw = &wqkvt[(size_t)widx * CC * CC + (size_t)(n0 + rS) * CC + sgS * 32];
#pragma unroll
      for (int j = 0; j < 4; ++j)
        *reinterpret_cast<u16x8*>(&wt[rS][sgS * 32 + j * 8]) = *reinterpret_cast<const u16x8*>(&sw[j * 8]);
    }
    __syncthreads();
    if (widx < 2) {
      const float* bias = (widx == 0) ? bq : bk;
      u16* outp = (widx == 0) ? qo : ko;
      const float oscale = (widx == 0) ? SCALE_L2E : 1.0f;
      f32x4 acc[4];
#pragma unroll
      for (int st = 0; st < 4; ++st) {
        const float b_ = bias[n0 + st * 16 + lo];
        acc[st] = (f32x4){b_, b_, b_, b_};
      }
#pragma unroll
      for (int kk = 0; kk < 4; ++kk) {
        const bf16x8 af = *reinterpret_cast<const bf16x8*>(&xs[w * 16 + lo][kk * 32 + 8 * hi]);
#pragma unroll
        for (int st = 0; st < 4; ++st) {
          const bf16x8 bfr = *reinterpret_cast<const bf16x8*>(&wt[st * 16 + lo][kk * 32 + 8 * hi]);
          acc[st] = __builtin_amdgcn_mfma_f32_16x16x32_bf16(af, bfr, acc[st], 0, 0, 0);
        }
      }
#pragma unroll
      for (int r = 0; r < 4; ++r) {
        const int mm = m0 + w * 16 + hi4 + r;
        size_t rowbase, hstride;
        if (PATH == 0) {
          const int win = mm / 49, tok = mm - win * 49;
          rowbase = ((size_t)(win * 4) * 49 + tok) * DK;
          hstride = (size_t)49 * DK;
        } else {
          const int b = mm / S_GLB, s = mm - b * S_GLB;
          rowbase = ((size_t)(b * 4) * S_GLB + s) * DK;
          hstride = (size_t)S_GLB * DK;
        }
#pragma unroll
        for (int st = 0; st < 4; ++st) {
          const int c = n0 + st * 16 + lo, h = c >> 5, d = c & 31;
          outp[rowbase + (size_t)h * hstride + d] = f2bf(acc[st][r] * oscale);
        }
      }
    } else {
      f32x4 bias4;
#pragma unroll
      for (int r = 0; r < 4; ++r) bias4[r] = bv[n0 + w * 16 + hi4 + r];
      f32x4 acc[4];
#pragma unroll
      for (int st = 0; st < 4; ++st) acc[st] = bias4;
#pragma unroll
      for (int kk = 0; kk < 4; ++kk) {
        const bf16x8 af = *reinterpret_cast<const bf16x8*>(&wt[w * 16 + lo][kk * 32 + 8 * hi]);
#pragma unroll
        for (int st = 0; st < 4; ++st) {
          const bf16x8 bfr = *reinterpret_cast<const bf16x8*>(&xs[st * 16 + lo][kk * 32 + 8 * hi]);
          acc[st] = __builtin_amdgcn_mfma_f32_16x16x32_bf16(af, bfr, acc[st], 0, 0, 0);
        }
      }
#pragma unroll
      for (int st = 0; st < 4; ++st) {
        const int mm = m0 + st * 16 + lo;
#pragma unroll
        for (int r = 0; r < 4; ++r) {
          const int c = n0 + w * 16 + hi4 + r;
          if (PATH == 0) {
            vto[(size_t)c * VTW_STRIDE + mm] = f2bf(acc[st][r]);
          } else {
            const int b = mm / S_GLB, s = mm - b * S_GLB;
            vto[((size_t)b * CC + c) * S_GLB + s] = f2bf(acc[st][r]);
          }
        }
      }
    }
  }
}

// ---------------- window attention: no-max exp2 softmax, l via ones-MFMA
__global__ __launch_bounds__(256) void win_attn_k(
    const u16* __restrict__ qw, const u16* __restrict__ kw,
    const u16* __restrict__ vtw, u16* __restrict__ aow) {
  __shared__ __align__(16) u16 psh[4][16][72];
  const int tid = threadIdx.x;
  const int wvi = tid >> 6, lane = tid & 63;
  const int lo = lane & 15, hi = lane >> 4, hi4 = hi * 4;
  const int wh = blockIdx.x * 4 + wvi;
  const int win = wh >> 2, hd = wh & 3;
  const f32x4 zero4 = {0.f, 0.f, 0.f, 0.f};
  bf16x8 ones;
#pragma unroll
  for (int j = 0; j < 8; ++j) ones[j] = (short)0x3F80;

  bf16x8 kf[4], vf[2][2];
#pragma unroll
  for (int st = 0; st < 4; ++st)
    kf[st] = *reinterpret_cast<const bf16x8*>(&kw[((size_t)wh * 49 + st * 16 + lo) * DK + 8 * hi]);
#pragma unroll
  for (int dst = 0; dst < 2; ++dst)
#pragma unroll
    for (int kch = 0; kch < 2; ++kch)
      vf[dst][kch] = *reinterpret_cast<const bf16x8*>(
          &vtw[(size_t)(hd * DK + dst * 16 + lo) * VTW_STRIDE + win * 49 + kch * 32 + 8 * hi]);

#pragma unroll
  for (int g = 0; g < 4; ++g) {
    const bf16x8 qf = *reinterpret_cast<const bf16x8*>(
        &qw[((size_t)wh * 49 + g * 16 + lo) * DK + 8 * hi]);
    f32x4 s4[4];
#pragma unroll
    for (int st = 0; st < 4; ++st) {
      s4[st] = __builtin_amdgcn_mfma_f32_16x16x32_bf16(kf[st], qf, zero4, 0, 0, 0);
#pragma unroll
      for (int r = 0; r < 4; ++r)
        if (st * 16 + hi4 + r >= 49) s4[st][r] = -1e30f;  // mask pad keys -> p=0
    }
#pragma unroll
    for (int st = 0; st < 4; ++st) {
      uint2 pk;
      pk.x = pk2bf(fexp2(s4[st][0]), fexp2(s4[st][1]));
      pk.y = pk2bf(fexp2(s4[st][2]), fexp2(s4[st][3]));
      *reinterpret_cast<uint2*>(&psh[wvi][lo][st * 16 + hi4]) = pk;
    }
    asm volatile("" ::: "memory");
    f32x4 acc0 = zero4, acc1 = zero4, lacc = zero4;
#pragma unroll
    for (int kch = 0; kch < 2; ++kch) {
      const bf16x8 pa = *reinterpret_cast<const bf16x8*>(&psh[wvi][lo][kch * 32 + 8 * hi]);
      acc0 = __builtin_amdgcn_mfma_f32_16x16x32_bf16(pa, vf[0][kch], acc0, 0, 0, 0);
      acc1 = __builtin_amdgcn_mfma_f32_16x16x32_bf16(pa, vf[1][kch], acc1, 0, 0, 0);
      lacc = __builtin_amdgcn_mfma_f32_16x16x32_bf16(pa, ones, lacc, 0, 0, 0);
    }
#pragma unroll
    for (int r = 0; r < 4; ++r) {
      const int qrow = g * 16 + hi4 + r;
      if (qrow < 49) {
        const float rl = 1.0f / lacc[r];
        const size_t tw = (size_t)win * 49 + qrow;
        aow[tw * CC + hd * DK + lo] = f2bf(acc0[r] * rl);
        aow[tw * CC + hd * DK + 16 + lo] = f2bf(acc1[r] * rl);
      }
    }
  }
}

// ---------------- global attention: split-K, 4-wave 2-buffer 2-phase,
// XCD-bijective swizzle. Partial O stored as bf16 (halves po traffic).
__global__ __launch_bounds__(256) void glb_attn_k(
    const u16* __restrict__ qg, const u16* __restrict__ kg,
    const u16* __restrict__ vtg, u16* __restrict__ po, float* __restrict__ pl) {
  __shared__ __align__(16) u16 ksh[2][64][32];   // linear, conflict-free reads
  __shared__ __align__(16) u16 vtsh[2][32][64];  // content XOR-swizzled via source
  __shared__ __align__(16) u16 psh[4][16][64];   // XOR-swizzled write/read
  const int tid = threadIdx.x;
  const int w = tid >> 6, lane = tid & 63;
  const int lo = lane & 15, hi = lane >> 4, hi4 = hi * 4;
  // XCD-bijective swizzle: 1568 blocks = 8 XCDs x 196.
  const int wg = blockIdx.x;
  const int sid = (wg & 7) * 196 + (wg >> 3);
  const int sp = sid / 784;
  const int rem = sid - sp * 784;
  const int bh = rem / 49;
  const int q0 = (rem - bh * 49) * 64;
  const int kt_beg = sp * 25;
  const int kt_end = sp ? 49 : 25;
  const f32x4 zero4 = {0.f, 0.f, 0.f, 0.f};
  bf16x8 ones;
#pragma unroll
  for (int j = 0; j < 8; ++j) ones[j] = (short)0x3F80;

  const bf16x8 qfrag = *reinterpret_cast<const bf16x8*>(
      &qg[((size_t)bh * S_GLB + q0 + w * 16 + lo) * DK + 8 * hi]);
  const u16* kg0 = kg + (size_t)bh * S_GLB * DK;
  const u16* vg0 = vtg + (size_t)bh * DK * S_GLB;

  const u16* ksrc = kg0 + (size_t)(w * 16 + (lane >> 2)) * DK + (lane & 3) * 8;
  const u16* vsrc = vg0 + (size_t)(w * 8 + (lane >> 3)) * S_GLB + ((lane & 7) ^ (lane >> 3)) * 8;
  u16* kdst0 = &ksh[0][w * 16][0]; u16* kdst1 = &ksh[1][w * 16][0];
  u16* vdst0 = &vtsh[0][w * 8][0]; u16* vdst1 = &vtsh[1][w * 8][0];

  f32x4 oacc0 = zero4, oacc1 = zero4, lacc = zero4;

  gload16(ksrc + (size_t)kt_beg * 64 * DK, kdst0);
  gload16(vsrc + (size_t)kt_beg * 64, vdst0);
  __syncthreads();

  char* const pbase = (char*)&psh[w][lo][0];
  char* const vbase0 = (char*)&vtsh[0][0][0];
  const unsigned swz = (unsigned)(lo & 7) << 4;

  for (int kt = kt_beg; kt < kt_end; ++kt) {
    const int cur = (kt - kt_beg) & 1;
    if (kt + 1 < kt_end) {  // issue next-tile DMA before compute (2-phase)
      gload16(ksrc + (size_t)(kt + 1) * 64 * DK, cur ? kdst0 : kdst1);
      gload16(vsrc + (size_t)(kt + 1) * 64, cur ? vdst0 : vdst1);
    }
    // S^T = K * Q^T
    f32x4 s4[4];
#pragma unroll
    for (int st = 0; st < 4; ++st) {
      const bf16x8 kfrag = *reinterpret_cast<const bf16x8*>(&ksh[cur][st * 16 + lo][8 * hi]);
      s4[st] = __builtin_amdgcn_mfma_f32_16x16x32_bf16(kfrag, qfrag, zero4, 0, 0, 0);
    }
    // p = exp2(s), pack to bf16, swizzled P store
#pragma unroll
    for (int st = 0; st < 4; ++st) {
      uint2 pk;
      pk.x = pk2bf(fexp2(s4[st][0]), fexp2(s4[st][1]));
      pk.y = pk2bf(fexp2(s4[st][2]), fexp2(s4[st][3]));
      *reinterpret_cast<uint2*>(pbase + (((unsigned)(st * 32 + hi * 8)) ^ swz)) = pk;
    }
    asm volatile("" ::: "memory");
    // PV + l via ones-MFMA
    char* const vrow0 = vbase0 + (size_t)cur * (32 * 64 * 2) + lo * 128;
#pragma unroll
    for (int kch = 0; kch < 2; ++kch) {
      const unsigned off = ((unsigned)(kch * 64 + hi * 16)) ^ swz;
      const bf16x8 pa = *reinterpret_cast<const bf16x8*>(pbase + off);
      const bf16x8 v0 = *reinterpret_cast<const bf16x8*>(vrow0 + off);
      const bf16x8 v1 = *reinterpret_cast<const bf16x8*>(vrow0 + 16 * 128 + off);
      oacc0 = __builtin_amdgcn_mfma_f32_16x16x32_bf16(pa, v0, oacc0, 0, 0, 0);
      oacc1 = __builtin_amdgcn_mfma_f32_16x16x32_bf16(pa, v1, oacc1, 0, 0, 0);
      lacc = __builtin_amdgcn_mfma_f32_16x16x32_bf16(pa, ones, lacc, 0, 0, 0);
    }
    __syncthreads();  // drains vmcnt: next tile landed; cur free to overwrite
  }

  const int b = bh >> 2, hd = bh & 3;
  u16* pob = po + (size_t)sp * NTOK * CC;
#pragma unroll
  for (int r = 0; r < 4; ++r) {
    const size_t t = (size_t)b * S_GLB + q0 + w * 16 + hi4 + r;
    pob[t * CC + hd * DK + lo] = f2bf(oacc0[r]);
    pob[t * CC + hd * DK + 16 + lo] = f2bf(oacc1[r]);
    if (lo == 0)
      pl[((size_t)sp * 16 + bh) * S_GLB + q0 + w * 16 + hi4 + r] = lacc[r];
  }
}

// ---------------- output projection GEMM with FUSED LayerNorm epilogue.
template <int MODE>
__global__ __launch_bounds__(256) void proj_ln_k(
    const u16* __restrict__ ain, const u16* __restrict__ po,
    const float* __restrict__ pl, const u16* __restrict__ wot,
    const float* __restrict__ bo, const float* __restrict__ resid,
    const float* __restrict__ lng, const float* __restrict__ lnb,
    float* __restrict__ xfo, u16* __restrict__ ybf) {
  __shared__ __align__(16) u16 xs[64][136];
  __shared__ __align__(16) u16 wt[128][136];
  const int tid = threadIdx.x;
  const int w = tid >> 6, lane = tid & 63;
  const int lo = lane & 15, hi = lane >> 4, hi4 = hi * 4;
  const int m0 = blockIdx.x * 64;
  {
    const int r = tid >> 2, sg = tid & 3;
    if (MODE == 0) {
      const u16* sx = &ain[(size_t)(m0 + r) * CC + sg * 32];
#pragma unroll
      for (int j = 0; j < 4; ++j)
        *reinterpret_cast<u16x8*>(&xs[r][sg * 32 + j * 8]) = *reinterpret_cast<const u16x8*>(&sx[j * 8]);
    } else {
      // fused split-K combine (bf16 partials): head == sg (32 channels/head)
      const int mm = m0 + r;
      const int b = mm / S_GLB, s_ = mm - b * S_GLB;
      const float l0 = pl[((size_t)(b * 4 + sg)) * S_GLB + s_];
      const float l1 = pl[((size_t)(16 + b * 4 + sg)) * S_GLB + s_];
      const float rl = 1.0f / (l0 + l1);
      const u16* pa = &po[(size_t)mm * CC + sg * 32];
      const u16* pb = pa + (size_t)NTOK * CC;
#pragma unroll
      for (int j = 0; j < 32; j += 8) {
        const u16x8 a8 = *reinterpret_cast<const u16x8*>(&pa[j]);
        const u16x8 b8 = *reinterpret_cast<const u16x8*>(&pb[j]);
        uint2 pk0, pk1;
        pk0.x = pk2bf((bf2f(a8[0]) + bf2f(b8[0])) * rl, (bf2f(a8[1]) + bf2f(b8[1])) * rl);
        pk0.y = pk2bf((bf2f(a8[2]) + bf2f(b8[2])) * rl, (bf2f(a8[3]) + bf2f(b8[3])) * rl);
        pk1.x = pk2bf((bf2f(a8[4]) + bf2f(b8[4])) * rl, (bf2f(a8[5]) + bf2f(b8[5])) * rl);
        pk1.y = pk2bf((bf2f(a8[6]) + bf2f(b8[6])) * rl, (bf2f(a8[7]) + bf2f(b8[7])) * rl);
        *reinterpret_cast<uint2*>(&xs[r][sg * 32 + j]) = pk0;
        *reinterpret_cast<uint2*>(&xs[r][sg * 32 + j + 4]) = pk1;
      }
    }
    // weights: 128 rows x 128 cols
    const int r2 = tid >> 1, sg2 = tid & 1;
    const u16* sw = &wot[(size_t)r2 * CC + sg2 * 64];
#pragma unroll
    for (int j = 0; j < 8; ++j)
      *reinterpret_cast<u16x8*>(&wt[r2][sg2 * 64 + j * 8]) = *reinterpret_cast<const u16x8*>(&sw[j * 8]);
  }
  __syncthreads();
  f32x4 acc[8];
#pragma unroll
  for (int st = 0; st < 8; ++st) {
    const float b_ = bo[st * 16 + lo];
    acc[st] = (f32x4){b_, b_, b_, b_};
  }
#pragma unroll
  for (int kk = 0; kk < 4; ++kk) {
    const bf16x8 af = *reinterpret_cast<const bf16x8*>(&xs[w * 16 + lo][kk * 32 + 8 * hi]);
#pragma unroll
    for (int st = 0; st < 8; ++st) {
      const bf16x8 bfr = *reinterpret_cast<const bf16x8*>(&wt[st * 16 + lo][kk * 32 + 8 * hi]);
      acc[st] = __builtin_amdgcn_mfma_f32_16x16x32_bf16(af, bfr, acc[st], 0, 0, 0);
    }
  }
  float gv[8], bv2[8];
#pragma unroll
  for (int st = 0; st < 8; ++st) { gv[st] = lng[st * 16 + lo]; bv2[st] = lnb[st * 16 + lo]; }
#pragma unroll
  for (int r = 0; r < 4; ++r) {
    const int mm = m0 + w * 16 + hi4 + r;
    size_t trow;
    if (MODE == 0) {
      const int win = mm / 49, tok = mm - win * 49;
      const int b = win >> 6, wi = (win >> 3) & 7, wj = win & 7;
      const int ii = tok / 7, jj = tok - ii * 7;
      int hr = wi * 7 + ii + SHIFT; if (hr >= HW) hr -= HW;
      int wr = wj * 7 + jj + SHIFT; if (wr >= HW) wr -= HW;
      trow = (size_t)b * S_GLB + hr * HW + wr;
    } else {
      trow = (size_t)mm;
    }
    float v[8];
    float s = 0.f, sq = 0.f;
#pragma unroll
    for (int st = 0; st < 8; ++st) {
      float t_ = acc[st][r];
      if (MODE == 1) t_ += resid[trow * CC + st * 16 + lo];
      v[st] = t_;
      s += t_;
      sq += t_ * t_;
    }
    s += __shfl_xor(s, 1); s += __shfl_xor(s, 2); s += __shfl_xor(s, 4); s += __shfl_xor(s, 8);
    sq += __shfl_xor(sq, 1); sq += __shfl_xor(sq, 2); sq += __shfl_xor(sq, 4); sq += __shfl_xor(sq, 8);
    const float mu = s * 0.0078125f;
    const float rsig = rsqrtf(sq * 0.0078125f - mu * mu + 1e-5f);
#pragma unroll
    for (int st = 0; st < 8; ++st) {
      const size_t idx = trow * CC + st * 16 + lo;
      xfo[idx] = v[st];
      ybf[idx] = f2bf((v[st] - mu) * rsig * gv[st] + bv2[st]);
    }
  }
}

// ---------------- GEMM1 [NTOK,128]@[128,512] + gelu -> bf16
__global__ __launch_bounds__(256) void gemm1_k(
    const u16* __restrict__ ybf, const u16* __restrict__ w1t,
    const float* __restrict__ b1, u16* __restrict__ hb) {
  __shared__ __align__(16) u16 xs[64][136];
  __shared__ __align__(16) u16 wt[64][136];
  const int tid = threadIdx.x;
  const int w = tid >> 6, lane = tid & 63;
  const int lo = lane & 15, hi = lane >> 4;
  const int m0 = blockIdx.x * 64, n0 = blockIdx.y * 64;
  {
    const int r = tid >> 2, sg = tid & 3;
    const u16* src_x = &ybf[(size_t)(m0 + r) * CC + sg * 32];
    const u16* src_w = &w1t[(size_t)(n0 + r) * CC + sg * 32];
#pragma unroll
    for (int j = 0; j < 4; ++j) {
      *reinterpret_cast<u16x8*>(&xs[r][sg * 32 + j * 8]) = *reinterpret_cast<const u16x8*>(&src_x[j * 8]);
      *reinterpret_cast<u16x8*>(&wt[r][sg * 32 + j * 8]) = *reinterpret_cast<const u16x8*>(&src_w[j * 8]);
    }
  }
  __syncthreads();
  f32x4 acc[4];
#pragma unroll
  for (int st = 0; st < 4; ++st) {
    const float bv = b1[n0 + st * 16 + lo];
    acc[st] = (f32x4){bv, bv, bv, bv};
  }
#pragma unroll
  for (int kk = 0; kk < 4; ++kk) {
    const bf16x8 af = *reinterpret_cast<const bf16x8*>(&xs[w * 16 + lo][kk * 32 + 8 * hi]);
#pragma unroll
    for (int st = 0; st < 4; ++st) {
      const bf16x8 bfr = *reinterpret_cast<const bf16x8*>(&wt[st * 16 + lo][kk * 32 + 8 * hi]);
      acc[st] = __builtin_amdgcn_mfma_f32_16x16x32_bf16(af, bfr, acc[st], 0, 0, 0);
    }
  }
#pragma unroll
  for (int st = 0; st < 4; ++st) {
#pragma unroll
    for (int r = 0; r < 4; ++r) {
      const float val = acc[st][r];
      const float gel = 0.5f * val * (1.0f + erff(val * 0.70710678118f));
      hb[(size_t)(m0 + w * 16 + (hi << 2) + r) * 512 + n0 + st * 16 + lo] = f2bf(gel);
    }
  }
}

// ---------------- GEMM2 [NTOK,512]@[512,128] + residual -> out
__global__ __launch_bounds__(256) void gemm2_k(
    const u16* __restrict__ hb, const u16* __restrict__ w2t,
    const float* __restrict__ b2, const float* __restrict__ xf,
    float* __restrict__ out) {
  __shared__ __align__(16) u16 xs[64][136];
  __shared__ __align__(16) u16 wt[64][136];
  const int tid = threadIdx.x;
  const int w = tid >> 6, lane = tid & 63;
  const int lo = lane & 15, hi = lane >> 4;
  const int m0 = blockIdx.x * 64, n0 = blockIdx.y * 64;
  f32x4 acc[4];
#pragma unroll
  for (int st = 0; st < 4; ++st) {
    const float bv = b2[n0 + st * 16 + lo];
    acc[st] = (f32x4){bv, bv, bv, bv};
  }
  for (int kc = 0; kc < 4; ++kc) {
    if (kc) __syncthreads();
    {
      const int r = tid >> 2, sg = tid & 3;
      const u16* src_x = &hb[(size_t)(m0 + r) * 512 + kc * 128 + sg * 32];
      const u16* src_w = &w2t[(size_t)(n0 + r) * 512 + kc * 128 + sg * 32];
#pragma unroll
      for (int j = 0; j < 4; ++j) {
        *reinterpret_cast<u16x8*>(&xs[r][sg * 32 + j * 8]) = *reinterpret_cast<const u16x8*>(&src_x[j * 8]);
        *reinterpret_cast<u16x8*>(&wt[r][sg * 32 + j * 8]) = *reinterpret_cast<const u16x8*>(&src_w[j * 8]);
      }
    }
    __syncthreads();
#pragma unroll
    for (int kk = 0; kk < 4; ++kk) {
      const bf16x8 af = *reinterpret_cast<const bf16x8*>(&xs[w * 16 + lo][kk * 32 + 8 * hi]);
#pragma unroll
      for (int st = 0; st < 4; ++st) {
        const bf16x8 bfr = *reinterpret_cast<const bf16x8*>(&wt[st * 16 + lo][kk * 32 + 8 * hi]);
        acc[st] = __builtin_amdgcn_mfma_f32_16x16x32_bf16(af, bfr, acc[st], 0, 0, 0);
      }
    }
  }
#pragma unroll
  for (int st = 0; st < 4; ++st) {
#pragma unroll
    for (int r = 0; r < 4; ++r) {
      const size_t idx = (size_t)(m0 + w * 16 + (hi << 2) + r) * CC + n0 + st * 16 + lo;
      out[idx] = xf[idx] + acc[st][r];
    }
  }
}

extern "C" void kernel_launch(void* const* d_in, const int* in_sizes, int n_in,
                              void* d_out, int out_size, void* d_ws, size_t ws_size,
                              hipStream_t stream) {
  (void)in_sizes; (void)n_in; (void)out_size; (void)ws_size;
  const float* x   = (const float*)d_in[0];
  const float* wq  = (const float*)d_in[1];
  const float* bq  = (const float*)d_in[2];
  const float* wk  = (const float*)d_in[3];
  const float* bk  = (const float*)d_in[4];
  const float* wv  = (const float*)d_in[5];
  const float* bv  = (const float*)d_in[6];
  const float* wo  = (const float*)d_in[7];
  const float* bo  = (const float*)d_in[8];
  const float* w1  = (const float*)d_in[9];
  const float* b1  = (const float*)d_in[10];
  const float* w2  = (const float*)d_in[11];
  const float* b2  = (const float*)d_in[12];
  const float* g1  = (const float*)d_in[13];
  const float* be1 = (const float*)d_in[14];
  const float* g2  = (const float*)d_in[15];
  const float* be2 = (const float*)d_in[16];
  float* out = (float*)d_out;

  char* p = (char*)d_ws;
  auto alloc = [&](size_t bytes) { char* r = p; p += (bytes + 255) & ~(size_t)255; return r; };
  float* xf  = (float*)alloc((size_t)NTOK * CC * 4);
  u16* xg    = (u16*)alloc((size_t)NTOK * CC * 2);   // gather out / LN out (ybf)
  u16* qw    = (u16*)alloc((size_t)NTOK * CC * 2 + 4096);
  u16* kw    = (u16*)alloc((size_t)NTOK * CC * 2 + 4096);
  u16* vtw   = (u16*)alloc((size_t)CC * VTW_STRIDE * 2);
  u16* aow   = (u16*)alloc((size_t)NTOK * CC * 2);
  u16* hb    = (u16*)alloc((size_t)NTOK * 512 * 2);
  u16* po    = (u16*)alloc((size_t)2 * NTOK * CC * 2);
  float* pl  = (float*)alloc((size_t)2 * 16 * S_GLB * 4);
  u16* wqkvt = (u16*)alloc(3 * 16384 * 2);
  u16* wot   = (u16*)alloc(16384 * 2);
  u16* w1t   = (u16*)alloc(65536 * 2);
  u16* w2t   = (u16*)alloc(65536 * 2);

  prep_k<<<768 + NTOK / 2, 256, 0, stream>>>(
      w1, w2, wq, wk, wv, wo, x, w1t, w2t, wqkvt, wot, xg);
  qkv_gemm_k<0><<<dim3(NTOK / 64, 3), 256, 0, stream>>>(xg, wqkvt, bq, bk, bv, qw, kw, vtw);
  win_attn_k<<<256, 256, 0, stream>>>(qw, kw, vtw, aow);
  proj_ln_k<0><<<NTOK / 64, 256, 0, stream>>>(
      aow, nullptr, nullptr, wot, bo, nullptr, g1, be1, xf, xg);
  qkv_gemm_k<1><<<dim3(NTOK / 64, 3), 256, 0, stream>>>(xg, wqkvt, bq, bk, bv, qw, kw, vtw);
  glb_attn_k<<<1568, 256, 0, stream>>>(qw, kw, vtw, po, pl);
  proj_ln_k<1><<<NTOK / 64, 256, 0, stream>>>(
      nullptr, po, pl, wot, bo, xf, g2, be2, xf, xg);
  gemm1_k<<<dim3(NTOK / 64, 8), 256, 0, stream>>>(xg, w1t, b1, hb);
  gemm2_k<<<dim3(NTOK / 64, 2), 256, 0, stream>>>(hb, w2t, b2, xf, out);
}